// Round 2
// baseline (232.680 us; speedup 1.0000x reference)
//
#include <hip/hip_runtime.h>
#include <hip/hip_bf16.h>
#include <stdint.h>

typedef __bf16 bf16;
typedef bf16 bf16x8 __attribute__((ext_vector_type(8)));
typedef float f32x4 __attribute__((ext_vector_type(4)));
typedef float f32x16 __attribute__((ext_vector_type(16)));

// ---------------- tiny prep kernels ----------------

// s[b,c] = style[b,:] . style_w[c,:] + style_b[c]
__global__ void k_style(const float* __restrict__ style, const float* __restrict__ sw,
                        const float* __restrict__ sbias, float* __restrict__ s_out) {
    int gw = (blockIdx.x * blockDim.x + threadIdx.x) >> 6;
    int lane = threadIdx.x & 63;
    if (gw >= 512) return;
    int b = gw >> 7, c = gw & 127;
    const float* st = style + b * 512;
    const float* wr = sw + c * 512;
    float a = 0.f;
#pragma unroll
    for (int j = 0; j < 8; ++j) a += st[lane + 64 * j] * wr[lane + 64 * j];
    for (int off = 32; off > 0; off >>= 1) a += __shfl_down(a, off, 64);
    if (lane == 0) s_out[gw] = a + sbias[c];
}

// sig_inv[b,o] = rsqrt( sum_i (sum_tap W[o,i,tap]^2) * s[b,i]^2 + 1e-8 )
__global__ void k_sig(const float* __restrict__ weight, const float* __restrict__ s,
                      float* __restrict__ sig) {
    int gw = (blockIdx.x * blockDim.x + threadIdx.x) >> 6;
    int lane = threadIdx.x & 63;
    if (gw >= 512) return;
    int b = gw >> 7, o = gw & 127;
    float a = 0.f;
#pragma unroll
    for (int j = 0; j < 2; ++j) {
        int i = lane + 64 * j;
        const float* wr = weight + ((size_t)o * 128 + i) * 9;
        float wsq = 0.f;
#pragma unroll
        for (int t = 0; t < 9; ++t) wsq += wr[t] * wr[t];
        float sv = s[b * 128 + i];
        a += wsq * sv * sv;
    }
    for (int off = 32; off > 0; off >>= 1) a += __shfl_down(a, off, 64);
    if (lane == 0) sig[gw] = rsqrtf(a + 1e-8f);
}

// repack weight fp32 [co][ci][9] -> bf16 wt[chunk8][tap9][g2][co128][8ci]
__global__ void k_wt(const float* __restrict__ weight, bf16* __restrict__ wt) {
    int i = blockIdx.x * 256 + threadIdx.x;
    if (i >= 147456) return;
    int j = i & 7;
    int co = (i >> 3) & 127;
    int g = (i >> 10) & 1;
    int tap = (i >> 11) % 9;
    int chunk = (i >> 11) / 9;
    int ci = chunk * 16 + g * 8 + j;
    wt[i] = (bf16)weight[((size_t)co * 128 + ci) * 9 + tap];
}

// ---------------- main MFMA conv kernel ----------------
// grid (4 wblk, 64 h, 4 b); block 512 = 8 waves; tile 128co x 256elem (16w x 16t)
// Wave tile 64co x 64el: acc[2][2] = 64 AGPR; (512,4) caps total regs at 128
// so 2 blocks/CU (LDS-capped at 55KB anyway) = 16 waves/CU.
// X staging is FUSED modulate+cast: raw fp32 x -> *s[b,ci] -> bf16 -> LDS,
// transposing ci into the inner dim (8ci per 16B cell). This deletes the
// separate 192MB k_xt pass. Staging temps live only before the tap loop so
// they reuse the tap-region register window (arch-VGPR cap ~64).
__global__ __launch_bounds__(512, 4) void conv_main(
    const float* __restrict__ x, const bf16* __restrict__ wt,
    const float* __restrict__ s, const float* __restrict__ sig_inv,
    const float* __restrict__ npar, const float* __restrict__ bpar,
    const float* __restrict__ noise, float* __restrict__ out) {
    __shared__ bf16 Xl[2][1728 * 8];   // 2 x 27648 B  [dh3][g2][e288][8ci]

    const int tid = threadIdx.x;
    const int lane = tid & 63;
    const int l31 = lane & 31, lhi = lane >> 5;
    const int wm = (tid >> 6) & 1;     // co half (64co each)
    const int wn = tid >> 7;           // el quarter (64el each), 0..3
    const int w0 = blockIdx.x * 16;
    const int h = blockIdx.y;
    const int b = blockIdx.z;
    const size_t bHW = (size_t)b * 65536;

    // stage one X chunk: per cell u, load 8 ci-strided fp32, scale by s, cast.
    // e runs contiguously in (wa,t) so E = (w0-1)*16 + e + ha*1024 is linear
    // in e -> lane-coalesced dword loads per ci plane.
    auto stage = [&](int chunk, bf16* buf) {
        const float* sc = s + b * 128 + chunk * 16;
        f32x4 s0 = *(const f32x4*)&sc[0];
        f32x4 s1 = *(const f32x4*)&sc[4];
        f32x4 s2 = *(const f32x4*)&sc[8];
        f32x4 s3 = *(const f32x4*)&sc[12];
        const f32x4 z4 = {0.f, 0.f, 0.f, 0.f};
#pragma unroll
        for (int it = 0; it < 4; ++it) {
            int u = it * 512 + tid;
            if (u < 1728) {
                int dh = u / 576;
                int rem = u - dh * 576;
                int g = rem / 288;
                int e = rem - g * 288;
                int ha = h - 1 + dh;
                int wa = w0 - 1 + (e >> 4);
                bool ok = ((unsigned)ha < 64u) & ((unsigned)wa < 64u);
                int E = (ha * 64 + wa) * 16 + (e & 15);
                int Ec = ok ? E : 0;            // clamp: load is always in-bounds
                int cib = chunk * 16 + g * 8;
                const float* xp = x + (((size_t)(b * 128 + cib)) << 16) + Ec;
                f32x4 slo = g ? s2 : s0;
                f32x4 shi = g ? s3 : s1;
                slo = ok ? slo : z4;            // zero halo via the scale
                shi = ok ? shi : z4;
                bf16x8 v;
#pragma unroll
                for (int j = 0; j < 4; ++j)
                    v[j] = (bf16)(xp[(size_t)j << 16] * slo[j]);
#pragma unroll
                for (int j = 0; j < 4; ++j)
                    v[4 + j] = (bf16)(xp[(size_t)(4 + j) << 16] * shi[j]);
                *(bf16x8*)&buf[u * 8] = v;
            }
        }
    };

    f32x16 acc[2][2] = {};

    // prefetch epilogue noise early (independent of K-loop)
    const size_t ebase = bHW + (size_t)h * 1024 + w0 * 16 + wn * 64;
    float ns[2];
#pragma unroll
    for (int nf = 0; nf < 2; ++nf) ns[nf] = noise[ebase + nf * 32 + l31];

    stage(0, Xl[0]);

    for (int chunk = 0; chunk < 8; ++chunk) {
        __syncthreads();                       // buf[chunk] writes visible;
                                               // buf[chunk+1]'s old readers done
        if (chunk < 7) stage(chunk + 1, Xl[(chunk + 1) & 1]);
        const bf16* Xb = Xl[chunk & 1];

#pragma unroll
        for (int tap = 0; tap < 9; ++tap) {
            const int dh = tap / 3, dw = tap % 3;
            const bf16* wg = wt +
                ((size_t)((chunk * 9 + tap) * 2 + lhi) * 128 + wm * 64 + l31) * 8;
            bf16x8 a0 = *(const bf16x8*)&wg[0];
            bf16x8 a1 = *(const bf16x8*)&wg[32 * 8];
            const bf16* xb = &Xb[((dh * 2 + lhi) * 288 + dw * 16 + wn * 64 + l31) * 8];
            bf16x8 b0 = *(const bf16x8*)&xb[0];
            bf16x8 b1 = *(const bf16x8*)&xb[32 * 8];
            acc[0][0] = __builtin_amdgcn_mfma_f32_32x32x16_bf16(a0, b0, acc[0][0], 0, 0, 0);
            acc[0][1] = __builtin_amdgcn_mfma_f32_32x32x16_bf16(a0, b1, acc[0][1], 0, 0, 0);
            acc[1][0] = __builtin_amdgcn_mfma_f32_32x32x16_bf16(a1, b0, acc[1][0], 0, 0, 0);
            acc[1][1] = __builtin_amdgcn_mfma_f32_32x32x16_bf16(a1, b1, acc[1][1], 0, 0, 0);
        }
    }

    // epilogue: D col = lane&31 (elem), row = (reg&3)+8*(reg>>2)+4*lhi (co)
#pragma unroll
    for (int fm = 0; fm < 2; ++fm) {
        int cob = wm * 64 + fm * 32 + 4 * lhi;
#pragma unroll
        for (int q = 0; q < 4; ++q) {
            int co4 = cob + 8 * q;
            f32x4 sg = *(const f32x4*)&sig_inv[b * 128 + co4];
            f32x4 np4 = *(const f32x4*)&npar[co4];
            f32x4 bp4 = *(const f32x4*)&bpar[co4];
#pragma unroll
            for (int r = 0; r < 4; ++r) {
                int co = co4 + r;
                float* orow = out + ((size_t)(b * 128 + co) * 64 + h) * 1024 +
                              w0 * 16 + wn * 64;
#pragma unroll
                for (int nf = 0; nf < 2; ++nf) {
                    float v = acc[fm][nf][q * 4 + r];
                    orow[nf * 32 + l31] = v * sg[r] + np4[r] * ns[nf] + bp4[r];
                }
            }
        }
    }
}

// ---------------- fp32 fallback (ws too small) ----------------
__global__ void k_naive(const float* __restrict__ x, const float* __restrict__ weight,
                        const float* __restrict__ s, const float* __restrict__ sig,
                        const float* __restrict__ npar, const float* __restrict__ bpar,
                        const float* __restrict__ noise, float* __restrict__ out) {
    size_t o = (size_t)blockIdx.x * 256 + threadIdx.x;
    int t = o & 15, w = (o >> 4) & 63, h = (o >> 10) & 63;
    int co = (o >> 16) & 127, b = (int)(o >> 23);
    float a = 0.f;
    for (int ci = 0; ci < 128; ++ci) {
        const float* xr = x + (size_t)(b * 128 + ci) * 65536;
        const float* wr = weight + ((size_t)co * 128 + ci) * 9;
        float p = 0.f;
#pragma unroll
        for (int kh = 0; kh < 3; ++kh) {
            int ha = h + kh - 1;
            if ((unsigned)ha >= 64u) continue;
#pragma unroll
            for (int kw = 0; kw < 3; ++kw) {
                int wa = w + kw - 1;
                if ((unsigned)wa >= 64u) continue;
                p += xr[(ha * 64 + wa) * 16 + t] * wr[kh * 3 + kw];
            }
        }
        a += p * s[b * 128 + ci];
    }
    int E = b * 65536 + (h * 64 + w) * 16 + t;
    out[o] = a * sig[b * 128 + co] + npar[co] * noise[E] + bpar[co];
}

// ---------------- host ----------------
extern "C" void kernel_launch(void* const* d_in, const int* in_sizes, int n_in,
                              void* d_out, int out_size, void* d_ws, size_t ws_size,
                              hipStream_t stream) {
    const float* x      = (const float*)d_in[0];
    const float* style  = (const float*)d_in[1];
    const float* noise  = (const float*)d_in[2];
    const float* weight = (const float*)d_in[3];
    const float* sw     = (const float*)d_in[4];
    const float* sb     = (const float*)d_in[5];
    const float* npar   = (const float*)d_in[6];
    const float* bpar   = (const float*)d_in[7];
    float* out = (float*)d_out;

    float* s_buf   = (float*)d_ws;                         // 512 f32
    float* sig_buf = s_buf + 512;                          // 512 f32
    bf16*  wt      = (bf16*)((char*)d_ws + 8192);          // 294912 B
    const size_t NEED = 8192 + 294912ull;

    k_style<<<dim3(128), dim3(256), 0, stream>>>(style, sw, sb, s_buf);
    k_sig<<<dim3(128), dim3(256), 0, stream>>>(weight, s_buf, sig_buf);
    if (ws_size >= NEED) {
        k_wt<<<dim3(576), dim3(256), 0, stream>>>(weight, wt);
        conv_main<<<dim3(4, 64, 4), dim3(512), 0, stream>>>(
            x, wt, s_buf, sig_buf, npar, bpar, noise, out);
    } else {
        k_naive<<<dim3(131072), dim3(256), 0, stream>>>(
            x, weight, s_buf, sig_buf, npar, bpar, noise, out);
    }
}

// Round 3
// 129.920 us; speedup vs baseline: 1.7909x; 1.7909x over previous
//
#include <hip/hip_runtime.h>
#include <hip/hip_bf16.h>
#include <stdint.h>

typedef __bf16 bf16;
typedef bf16 bf16x8 __attribute__((ext_vector_type(8)));
typedef float f32x4 __attribute__((ext_vector_type(4)));
typedef float f32x16 __attribute__((ext_vector_type(16)));

// ---------------- tiny prep kernels ----------------

// s[b,c] = style[b,:] . style_w[c,:] + style_b[c]
__global__ void k_style(const float* __restrict__ style, const float* __restrict__ sw,
                        const float* __restrict__ sbias, float* __restrict__ s_out) {
    int gw = (blockIdx.x * blockDim.x + threadIdx.x) >> 6;
    int lane = threadIdx.x & 63;
    if (gw >= 512) return;
    int b = gw >> 7, c = gw & 127;
    const float* st = style + b * 512;
    const float* wr = sw + c * 512;
    float a = 0.f;
#pragma unroll
    for (int j = 0; j < 8; ++j) a += st[lane + 64 * j] * wr[lane + 64 * j];
    for (int off = 32; off > 0; off >>= 1) a += __shfl_down(a, off, 64);
    if (lane == 0) s_out[gw] = a + sbias[c];
}

// sig_inv[b,o] = rsqrt( sum_i (sum_tap W[o,i,tap]^2) * s[b,i]^2 + 1e-8 )
__global__ void k_sig(const float* __restrict__ weight, const float* __restrict__ s,
                      float* __restrict__ sig) {
    int gw = (blockIdx.x * blockDim.x + threadIdx.x) >> 6;
    int lane = threadIdx.x & 63;
    if (gw >= 512) return;
    int b = gw >> 7, o = gw & 127;
    float a = 0.f;
#pragma unroll
    for (int j = 0; j < 2; ++j) {
        int i = lane + 64 * j;
        const float* wr = weight + ((size_t)o * 128 + i) * 9;
        float wsq = 0.f;
#pragma unroll
        for (int t = 0; t < 9; ++t) wsq += wr[t] * wr[t];
        float sv = s[b * 128 + i];
        a += wsq * sv * sv;
    }
    for (int off = 32; off > 0; off >>= 1) a += __shfl_down(a, off, 64);
    if (lane == 0) sig[gw] = rsqrtf(a + 1e-8f);
}

// repack + style-fold: fp32 W[co][ci][9] * s[b][ci] ->
// bf16 wt[b4][chunk8][tap9][g2][co128][8ci]
__global__ void k_wt(const float* __restrict__ weight, const float* __restrict__ s,
                     bf16* __restrict__ wt) {
    int i = blockIdx.x * 256 + threadIdx.x;
    if (i >= 589824) return;
    int j = i & 7;
    int co = (i >> 3) & 127;
    int g = (i >> 10) & 1;
    int tap = (i >> 11) % 9;
    int cb = (i >> 11) / 9;      // chunk + 8*b
    int chunk = cb & 7, b = cb >> 3;
    int ci = chunk * 16 + g * 8 + j;
    wt[i] = (bf16)(weight[((size_t)co * 128 + ci) * 9 + tap] * s[b * 128 + ci]);
}

// ---------------- main MFMA conv kernel ----------------
// grid (4 wblk, 64 h, 4 b); block 256 = 4 waves; tile 128co x 256elem (16w x 16t)
// Wave tile 64co x 128el: acc[2][4] = 128 AGPR; (256,2) -> 128 arch VGPR,
// 2 independent blocks/CU (their barrier phases interleave).
// Style scale is FOLDED INTO PER-BATCH WEIGHTS (k_wt), so X staging from raw
// fp32 x is convert-only: 8 ci-strided coalesced dword loads -> bf16x8 ->
// ds_write_b128, halo zeroed by value-select. This deletes the 192MB k_xt
// pass. 128 arch VGPRs (vs round-2's 64) keep staging spill-free.
__global__ __launch_bounds__(256, 2) void conv_main(
    const float* __restrict__ x, const bf16* __restrict__ wt,
    const float* __restrict__ sig_inv, const float* __restrict__ npar,
    const float* __restrict__ bpar, const float* __restrict__ noise,
    float* __restrict__ out) {
    __shared__ bf16 Xl[2][1728 * 8];   // 2 x 27648 B  [dh3][g2][e288][8ci]

    const int tid = threadIdx.x;
    const int lane = tid & 63;
    const int l31 = lane & 31, lhi = lane >> 5;
    const int wm = (tid >> 6) & 1;     // co half (64co each)
    const int wn = tid >> 7;           // el half (128el each)
    const int w0 = blockIdx.x * 16;
    const int h = blockIdx.y;
    const int b = blockIdx.z;
    const size_t bHW = (size_t)b * 65536;

    // stage one X chunk (1728 cells, 6.75 cells/thread): per cell load 8
    // ci-planes (lane-coalesced dwords), cvt to bf16, zero halo, ds_write.
    auto stage = [&](int chunk, bf16* buf) {
        const bf16 zz = (bf16)0.f;
        const bf16x8 vz = {zz, zz, zz, zz, zz, zz, zz, zz};
#pragma unroll
        for (int it = 0; it < 7; ++it) {
            int u = it * 256 + tid;
            if (u < 1728) {              // iter 6: tid<192, wave-uniform cut
                int dh = u / 576;
                int rem = u - dh * 576;
                int g = rem / 288;
                int e = rem - g * 288;
                int ha = h - 1 + dh;
                int wa = w0 - 1 + (e >> 4);
                bool ok = ((unsigned)ha < 64u) & ((unsigned)wa < 64u);
                int E = (ha * 64 + wa) * 16 + (e & 15);
                int Ec = ok ? E : 0;     // clamp: loads always in-bounds
                const float* xp =
                    x + (((size_t)(b * 128 + chunk * 16 + g * 8)) << 16) + Ec;
                bf16x8 v;
#pragma unroll
                for (int j = 0; j < 8; ++j) v[j] = (bf16)xp[(size_t)j << 16];
                v = ok ? v : vz;         // halo -> exact zero
                *(bf16x8*)&buf[u * 8] = v;
            }
        }
    };

    f32x16 acc[2][4] = {};

    // prefetch epilogue noise early (independent of K-loop)
    const size_t ebase = bHW + (size_t)h * 1024 + w0 * 16 + wn * 128;
    float ns[4];
#pragma unroll
    for (int nf = 0; nf < 4; ++nf) ns[nf] = noise[ebase + nf * 32 + l31];

    stage(0, Xl[0]);

    for (int chunk = 0; chunk < 8; ++chunk) {
        __syncthreads();                       // buf[chunk] writes visible;
                                               // buf[chunk+1]'s old readers done
        if (chunk < 7) stage(chunk + 1, Xl[(chunk + 1) & 1]);
        const bf16* Xb = Xl[chunk & 1];
        const bf16* wb = wt + (size_t)b * 147456;

#pragma unroll
        for (int tap = 0; tap < 9; ++tap) {
            const int dh = tap / 3, dw = tap % 3;
            const bf16* wg = wb +
                ((size_t)((chunk * 9 + tap) * 2 + lhi) * 128 + wm * 64 + l31) * 8;
            bf16x8 a0 = *(const bf16x8*)&wg[0];
            bf16x8 a1 = *(const bf16x8*)&wg[32 * 8];
            const bf16* xb = &Xb[((dh * 2 + lhi) * 288 + dw * 16 + wn * 128 + l31) * 8];
            bf16x8 b0 = *(const bf16x8*)&xb[0];
            bf16x8 b1 = *(const bf16x8*)&xb[32 * 8];
            bf16x8 b2 = *(const bf16x8*)&xb[64 * 8];
            bf16x8 b3 = *(const bf16x8*)&xb[96 * 8];
            acc[0][0] = __builtin_amdgcn_mfma_f32_32x32x16_bf16(a0, b0, acc[0][0], 0, 0, 0);
            acc[0][1] = __builtin_amdgcn_mfma_f32_32x32x16_bf16(a0, b1, acc[0][1], 0, 0, 0);
            acc[0][2] = __builtin_amdgcn_mfma_f32_32x32x16_bf16(a0, b2, acc[0][2], 0, 0, 0);
            acc[0][3] = __builtin_amdgcn_mfma_f32_32x32x16_bf16(a0, b3, acc[0][3], 0, 0, 0);
            acc[1][0] = __builtin_amdgcn_mfma_f32_32x32x16_bf16(a1, b0, acc[1][0], 0, 0, 0);
            acc[1][1] = __builtin_amdgcn_mfma_f32_32x32x16_bf16(a1, b1, acc[1][1], 0, 0, 0);
            acc[1][2] = __builtin_amdgcn_mfma_f32_32x32x16_bf16(a1, b2, acc[1][2], 0, 0, 0);
            acc[1][3] = __builtin_amdgcn_mfma_f32_32x32x16_bf16(a1, b3, acc[1][3], 0, 0, 0);
        }
    }

    // epilogue: D col = lane&31 (elem), row = (reg&3)+8*(reg>>2)+4*lhi (co)
#pragma unroll
    for (int fm = 0; fm < 2; ++fm) {
        int cob = wm * 64 + fm * 32 + 4 * lhi;
#pragma unroll
        for (int q = 0; q < 4; ++q) {
            int co4 = cob + 8 * q;
            f32x4 sg = *(const f32x4*)&sig_inv[b * 128 + co4];
            f32x4 np4 = *(const f32x4*)&npar[co4];
            f32x4 bp4 = *(const f32x4*)&bpar[co4];
#pragma unroll
            for (int r = 0; r < 4; ++r) {
                int co = co4 + r;
                float* orow = out + ((size_t)(b * 128 + co) * 64 + h) * 1024 +
                              w0 * 16 + wn * 128;
#pragma unroll
                for (int nf = 0; nf < 4; ++nf) {
                    float v = acc[fm][nf][q * 4 + r];
                    orow[nf * 32 + l31] = v * sg[r] + np4[r] * ns[nf] + bp4[r];
                }
            }
        }
    }
}

// ---------------- fp32 fallback (ws too small) ----------------
__global__ void k_naive(const float* __restrict__ x, const float* __restrict__ weight,
                        const float* __restrict__ s, const float* __restrict__ sig,
                        const float* __restrict__ npar, const float* __restrict__ bpar,
                        const float* __restrict__ noise, float* __restrict__ out) {
    size_t o = (size_t)blockIdx.x * 256 + threadIdx.x;
    int t = o & 15, w = (o >> 4) & 63, h = (o >> 10) & 63;
    int co = (o >> 16) & 127, b = (int)(o >> 23);
    float a = 0.f;
    for (int ci = 0; ci < 128; ++ci) {
        const float* xr = x + (size_t)(b * 128 + ci) * 65536;
        const float* wr = weight + ((size_t)co * 128 + ci) * 9;
        float p = 0.f;
#pragma unroll
        for (int kh = 0; kh < 3; ++kh) {
            int ha = h + kh - 1;
            if ((unsigned)ha >= 64u) continue;
#pragma unroll
            for (int kw = 0; kw < 3; ++kw) {
                int wa = w + kw - 1;
                if ((unsigned)wa >= 64u) continue;
                p += xr[(ha * 64 + wa) * 16 + t] * wr[kh * 3 + kw];
            }
        }
        a += p * s[b * 128 + ci];
    }
    int E = b * 65536 + (h * 64 + w) * 16 + t;
    out[o] = a * sig[b * 128 + co] + npar[co] * noise[E] + bpar[co];
}

// ---------------- host ----------------
extern "C" void kernel_launch(void* const* d_in, const int* in_sizes, int n_in,
                              void* d_out, int out_size, void* d_ws, size_t ws_size,
                              hipStream_t stream) {
    const float* x      = (const float*)d_in[0];
    const float* style  = (const float*)d_in[1];
    const float* noise  = (const float*)d_in[2];
    const float* weight = (const float*)d_in[3];
    const float* sw     = (const float*)d_in[4];
    const float* sb     = (const float*)d_in[5];
    const float* npar   = (const float*)d_in[6];
    const float* bpar   = (const float*)d_in[7];
    float* out = (float*)d_out;

    float* s_buf   = (float*)d_ws;                         // 512 f32
    float* sig_buf = s_buf + 512;                          // 512 f32
    bf16*  wt      = (bf16*)((char*)d_ws + 8192);          // 4 x 294912 B
    const size_t NEED = 8192 + 4 * 294912ull;

    k_style<<<dim3(128), dim3(256), 0, stream>>>(style, sw, sb, s_buf);
    k_sig<<<dim3(128), dim3(256), 0, stream>>>(weight, s_buf, sig_buf);
    if (ws_size >= NEED) {
        k_wt<<<dim3(2304), dim3(256), 0, stream>>>(weight, s_buf, wt);
        conv_main<<<dim3(4, 64, 4), dim3(256), 0, stream>>>(
            x, wt, sig_buf, npar, bpar, noise, out);
    } else {
        k_naive<<<dim3(131072), dim3(256), 0, stream>>>(
            x, weight, s_buf, sig_buf, npar, bpar, noise, out);
    }
}